// Round 1
// baseline (768.426 us; speedup 1.0000x reference)
//
#include <hip/hip_runtime.h>
#include <stdint.h>
#include <stddef.h>

#define TOK 8192
#define H 1024
#define IDIM 2048
#define NE 32
#define BM 128
#define BN 64
#define BK 64
#define MAX_TILES 96

typedef __attribute__((ext_vector_type(8))) short short8;
typedef __attribute__((ext_vector_type(4))) float f32x4;
typedef __attribute__((ext_vector_type(4))) float float4v;
typedef __attribute__((ext_vector_type(2))) unsigned int uint2v;

// ---- helpers -------------------------------------------------------------

__device__ __forceinline__ unsigned short f2bf(float x) {   // RNE fp32->bf16
  unsigned u = __builtin_bit_cast(unsigned, x);
  u += 0x7fffu + ((u >> 16) & 1u);
  return (unsigned short)(u >> 16);
}

// async global->LDS, 16B per lane; LDS dest = wave-uniform base + lane*16
__device__ __forceinline__ void gll16(const void* g, void* l) {
  __builtin_amdgcn_global_load_lds(
      (const __attribute__((address_space(1))) unsigned int*)g,
      (__attribute__((address_space(3))) unsigned int*)l, 16, 0, 0);
}

__device__ __forceinline__ f32x4 mfma16(short8 a, short8 b, f32x4 c) {
  return __builtin_amdgcn_mfma_f32_16x16x32_bf16(a, b, c, 0, 0, 0);
}

// ---- 1) router: logits, top-1, sigmoid, bf16 casts ----------------------

__global__ __launch_bounds__(256) void router_kernel(
    const float* __restrict__ x, const float* __restrict__ gw,
    unsigned short* __restrict__ xbf, unsigned short* __restrict__ xsbf,
    int* __restrict__ expert_id, int* __restrict__ counts)
{
  __shared__ float xl[8 * H];          // 8 token rows, 32KB
  __shared__ float plog[8][8][NE];     // [chunk][tok][e]
  __shared__ float sscore[8];
  const int tid = threadIdx.x;
  const long t0 = (long)blockIdx.x * 8;

  const float4v* src = (const float4v*)(x + t0 * H);
  float4v* dst = (float4v*)xl;
  #pragma unroll
  for (int i = 0; i < 8; ++i) dst[tid + i * 256] = src[tid + i * 256];
  __syncthreads();

  {
    const int e = tid & 31, c = tid >> 5;
    float acc[8] = {0, 0, 0, 0, 0, 0, 0, 0};
    const float* gp = gw + (c * 128) * NE + e;
    for (int h = 0; h < 128; ++h) {
      float g = gp[h * NE];
      const float* xr = xl + (c * 128 + h);
      #pragma unroll
      for (int tk = 0; tk < 8; ++tk) acc[tk] += xr[tk * H] * g;
    }
    #pragma unroll
    for (int tk = 0; tk < 8; ++tk) plog[c][tk][e] = acc[tk];
  }
  __syncthreads();
  {
    const int e = tid & 31, tok = tid >> 5;
    float lg = 0.f;
    #pragma unroll
    for (int c = 0; c < 8; ++c) lg += plog[c][tok][e];
    float m = lg; int be = e;
    #pragma unroll
    for (int mask = 16; mask >= 1; mask >>= 1) {   // reduce within 32-lane group
      float om = __shfl_xor(m, mask);
      int   oe = __shfl_xor(be, mask);
      if (om > m || (om == m && oe < be)) { m = om; be = oe; }  // first-index tie
    }
    if (e == 0) {
      sscore[tok] = 1.f / (1.f + __expf(-m));
      expert_id[t0 + tok] = be;
      atomicAdd(&counts[be], 1);
    }
  }
  __syncthreads();
  {
    const float sc = sscore[tid >> 5];
    const int base = (tid >> 5) * H + (tid & 31) * 32;
    #pragma unroll
    for (int i = 0; i < 4; ++i) {
      short8 vx, vs;
      #pragma unroll
      for (int j = 0; j < 8; ++j) {
        float v = xl[base + i * 8 + j];
        vx[j] = (short)f2bf(v);
        vs[j] = (short)f2bf(v * sc);
      }
      *(short8*)(xbf  + t0 * H + base + i * 8) = vx;
      *(short8*)(xsbf + t0 * H + base + i * 8) = vs;
    }
  }
}

// ---- 2) scan: offsets, cursors, tile table ------------------------------

__global__ void scan_kernel(const int* __restrict__ counts, int* __restrict__ offsets,
                            int* __restrict__ cursor, int* __restrict__ tile_e,
                            int* __restrict__ tile_p, int* __restrict__ n_tiles)
{
  if (threadIdx.x != 0) return;
  int off = 0, nt = 0;
  for (int e = 0; e < NE; ++e) {
    offsets[e] = off; cursor[e] = off;
    int cc = counts[e];
    for (int k = 0; k < cc; k += BM) { tile_e[nt] = e; tile_p[nt] = off + k; ++nt; }
    off += cc;
  }
  offsets[NE] = off;
  n_tiles[0] = nt;
}

// ---- 3) perm build -------------------------------------------------------

__global__ __launch_bounds__(256) void perm_kernel(
    const int* __restrict__ expert_id, int* __restrict__ cursor, int* __restrict__ perm)
{
  int t = blockIdx.x * 256 + threadIdx.x;
  int e = expert_id[t];
  int pos = atomicAdd(&cursor[e], 1);
  perm[pos] = t;
}

// ---- 4) fused gate+up GEMM -> act = bf16(silu(xWg) * xWu) ---------------
// BM=128 x BN=64, BK=64, 4 waves (wave w owns rows [w*32,w*32+32) x all 64 cols).
// LDS rows are 128B, XOR-swizzled: byte_in_row ^= (row&7)<<4.

template<bool ROUTED>
__global__ __launch_bounds__(256, 2) void gateup_kernel(
    const unsigned short* __restrict__ Abase,
    const float* __restrict__ WgAll, const float* __restrict__ WuAll,
    unsigned short* __restrict__ act,
    const int* __restrict__ perm, const int* __restrict__ tile_e,
    const int* __restrict__ tile_p, const int* __restrict__ offsets,
    const int* __restrict__ n_tiles)
{
  __shared__ short Alds[BM * BK];   // 16KB, [row][k] swizzled
  __shared__ short Glds[BN * BK];   // 8KB,  [n][k] transposed+swizzled
  __shared__ short Ulds[BN * BK];

  const int tid = threadIdx.x;
  const int wave = tid >> 6, lane = tid & 63;

  int row0, row_end;
  const float *Wg, *Wu;
  if constexpr (ROUTED) {
    if ((int)blockIdx.x >= *n_tiles) return;
    const int e = tile_e[blockIdx.x];
    row0 = tile_p[blockIdx.x];
    row_end = offsets[e + 1];
    Wg = WgAll + (size_t)e * H * IDIM;
    Wu = WuAll + (size_t)e * H * IDIM;
  } else {
    row0 = blockIdx.x * BM; row_end = row0 + BM;
    Wg = WgAll; Wu = WuAll;
  }
  const int n0 = blockIdx.y * BN;

  // A staging descriptors (global src pre-swizzled; LDS dest linear per rule #21)
  const unsigned short* asrc[4];
  short* adst[4];
  #pragma unroll
  for (int i = 0; i < 4; ++i) {
    const int r = i * 32 + wave * 8 + (lane >> 3);
    int grow;
    if constexpr (ROUTED) {
      int p = row0 + r;
      if (p >= row_end) p = row0;       // clamp padded rows to a valid token
      grow = perm[p];
    } else grow = row0 + r;
    const int cb = ((lane & 7) * 16) ^ ((r & 7) << 4);
    asrc[i] = Abase + (size_t)grow * H + (cb >> 1);
    adst[i] = Alds + (i * 32 + wave * 8) * BK;   // wave-uniform
  }

  const int k4 = (tid & 15) * 4;   // W stage: 4x4 fp32 block per thread
  const int nj = (tid >> 4) * 4;

  f32x4 accg[2][4] = {};
  f32x4 accu[2][4] = {};

  for (int kt = 0; kt < H / BK; ++kt) {
    const int k0 = kt * BK;
    __syncthreads();                      // prev compute done
    #pragma unroll
    for (int i = 0; i < 4; ++i) gll16(asrc[i] + k0, adst[i]);

    float4v g4[4], u4[4];
    #pragma unroll
    for (int i = 0; i < 4; ++i) {
      g4[i] = *(const float4v*)(Wg + (size_t)(k0 + k4 + i) * IDIM + (n0 + nj));
      u4[i] = *(const float4v*)(Wu + (size_t)(k0 + k4 + i) * IDIM + (n0 + nj));
    }
    #pragma unroll
    for (int j = 0; j < 4; ++j) {
      const int n = nj + j;
      const int sb = (k4 * 2) ^ ((n & 7) << 4);
      uint2v pg, pu;
      pg.x = (unsigned)f2bf(g4[0][j]) | ((unsigned)f2bf(g4[1][j]) << 16);
      pg.y = (unsigned)f2bf(g4[2][j]) | ((unsigned)f2bf(g4[3][j]) << 16);
      pu.x = (unsigned)f2bf(u4[0][j]) | ((unsigned)f2bf(u4[1][j]) << 16);
      pu.y = (unsigned)f2bf(u4[2][j]) | ((unsigned)f2bf(u4[3][j]) << 16);
      *(uint2v*)((char*)Glds + n * 128 + sb) = pg;
      *(uint2v*)((char*)Ulds + n * 128 + sb) = pu;
    }
    __syncthreads();                      // staging visible (vmcnt drained)

    #pragma unroll
    for (int kk = 0; kk < 2; ++kk) {
      short8 af[2];
      #pragma unroll
      for (int m = 0; m < 2; ++m) {
        const int r = wave * 32 + m * 16 + (lane & 15);
        const int cb = (kk * 64 + ((lane >> 4) * 16)) ^ ((r & 7) << 4);
        af[m] = *(const short8*)((const char*)Alds + r * 128 + cb);
      }
      #pragma unroll
      for (int nf = 0; nf < 4; ++nf) {
        const int n = nf * 16 + (lane & 15);
        const int cb = (kk * 64 + ((lane >> 4) * 16)) ^ ((n & 7) << 4);
        short8 bg = *(const short8*)((const char*)Glds + n * 128 + cb);
        short8 bu = *(const short8*)((const char*)Ulds + n * 128 + cb);
        #pragma unroll
        for (int m = 0; m < 2; ++m) {
          accg[m][nf] = mfma16(af[m], bg, accg[m][nf]);
          accu[m][nf] = mfma16(af[m], bu, accu[m][nf]);
        }
      }
    }
  }

  // epilogue: silu(g)*u -> bf16 act
  #pragma unroll
  for (int m = 0; m < 2; ++m)
    #pragma unroll
    for (int nf = 0; nf < 4; ++nf) {
      const int col = n0 + nf * 16 + (lane & 15);
      #pragma unroll
      for (int j = 0; j < 4; ++j) {
        const int row = row0 + wave * 32 + m * 16 + ((lane >> 4) * 4) + j;
        if (ROUTED && row >= row_end) continue;
        const float g = accg[m][nf][j];
        const float u = accu[m][nf][j];
        const float v = (g / (1.f + __expf(-g))) * u;
        act[(size_t)row * IDIM + col] = f2bf(v);
      }
    }
}

// ---- 5) down GEMM: out = act @ Wd (+ scatter-add for routed) ------------

template<bool ROUTED>
__global__ __launch_bounds__(256, 2) void down_kernel(
    const unsigned short* __restrict__ act,
    const float* __restrict__ WdAll,
    float* __restrict__ out,
    const int* __restrict__ perm, const int* __restrict__ tile_e,
    const int* __restrict__ tile_p, const int* __restrict__ offsets,
    const int* __restrict__ n_tiles)
{
  __shared__ short Alds[BM * BK];   // 16KB
  __shared__ short Wlds[BN * BK];   // 8KB

  const int tid = threadIdx.x;
  const int wave = tid >> 6, lane = tid & 63;

  int row0, row_end;
  const float* Wd;
  if constexpr (ROUTED) {
    if ((int)blockIdx.x >= *n_tiles) return;
    const int e = tile_e[blockIdx.x];
    row0 = tile_p[blockIdx.x];
    row_end = offsets[e + 1];
    Wd = WdAll + (size_t)e * IDIM * H;
  } else {
    row0 = blockIdx.x * BM; row_end = row0 + BM;
    Wd = WdAll;
  }
  const int n0 = blockIdx.y * BN;

  const unsigned short* asrc[4];
  short* adst[4];
  #pragma unroll
  for (int i = 0; i < 4; ++i) {
    const int r = i * 32 + wave * 8 + (lane >> 3);
    int p = row0 + r;
    if (ROUTED && p >= row_end) p = row0;
    const int cb = ((lane & 7) * 16) ^ ((r & 7) << 4);
    asrc[i] = act + (size_t)p * IDIM + (cb >> 1);
    adst[i] = Alds + (i * 32 + wave * 8) * BK;
  }

  const int k4 = (tid & 15) * 4;
  const int nj = (tid >> 4) * 4;

  f32x4 acc[2][4] = {};

  for (int kt = 0; kt < IDIM / BK; ++kt) {
    const int k0 = kt * BK;
    __syncthreads();
    #pragma unroll
    for (int i = 0; i < 4; ++i) gll16(asrc[i] + k0, adst[i]);

    float4v w4[4];
    #pragma unroll
    for (int i = 0; i < 4; ++i)
      w4[i] = *(const float4v*)(Wd + (size_t)(k0 + k4 + i) * H + (n0 + nj));
    #pragma unroll
    for (int j = 0; j < 4; ++j) {
      const int n = nj + j;
      const int sb = (k4 * 2) ^ ((n & 7) << 4);
      uint2v pw;
      pw.x = (unsigned)f2bf(w4[0][j]) | ((unsigned)f2bf(w4[1][j]) << 16);
      pw.y = (unsigned)f2bf(w4[2][j]) | ((unsigned)f2bf(w4[3][j]) << 16);
      *(uint2v*)((char*)Wlds + n * 128 + sb) = pw;
    }
    __syncthreads();

    #pragma unroll
    for (int kk = 0; kk < 2; ++kk) {
      short8 af[2];
      #pragma unroll
      for (int m = 0; m < 2; ++m) {
        const int r = wave * 32 + m * 16 + (lane & 15);
        const int cb = (kk * 64 + ((lane >> 4) * 16)) ^ ((r & 7) << 4);
        af[m] = *(const short8*)((const char*)Alds + r * 128 + cb);
      }
      #pragma unroll
      for (int nf = 0; nf < 4; ++nf) {
        const int n = nf * 16 + (lane & 15);
        const int cb = (kk * 64 + ((lane >> 4) * 16)) ^ ((n & 7) << 4);
        short8 bw = *(const short8*)((const char*)Wlds + n * 128 + cb);
        #pragma unroll
        for (int m = 0; m < 2; ++m) acc[m][nf] = mfma16(af[m], bw, acc[m][nf]);
      }
    }
  }

  #pragma unroll
  for (int m = 0; m < 2; ++m)
    #pragma unroll
    for (int nf = 0; nf < 4; ++nf) {
      const int col = n0 + nf * 16 + (lane & 15);
      #pragma unroll
      for (int j = 0; j < 4; ++j) {
        const int row = row0 + wave * 32 + m * 16 + ((lane >> 4) * 4) + j;
        const float v = acc[m][nf][j];
        if constexpr (ROUTED) {
          if (row < row_end) {
            const int t = perm[row];
            out[(size_t)t * H + col] += v;     // shared pass wrote first
          }
        } else {
          out[(size_t)row * H + col] = v;
        }
      }
    }
}

// ---- launch --------------------------------------------------------------

extern "C" void kernel_launch(void* const* d_in, const int* in_sizes, int n_in,
                              void* d_out, int out_size, void* d_ws, size_t ws_size,
                              hipStream_t stream) {
  (void)in_sizes; (void)n_in; (void)out_size; (void)ws_size;
  const float* x      = (const float*)d_in[0];
  const float* gate_w = (const float*)d_in[1];
  const float* sgw    = (const float*)d_in[2];
  const float* suw    = (const float*)d_in[3];
  const float* sdw    = (const float*)d_in[4];
  const float* rgw    = (const float*)d_in[5];
  const float* ruw    = (const float*)d_in[6];
  const float* rdw    = (const float*)d_in[7];
  float* out = (float*)d_out;

  char* ws = (char*)d_ws;
  unsigned short* xbf  = (unsigned short*)(ws + 0);           // 16MB
  unsigned short* xsbf = (unsigned short*)(ws + 16777216);    // 16MB
  unsigned short* act  = (unsigned short*)(ws + 33554432);    // 32MB
  int* perm      = (int*)(ws + 67108864);                     // 32KB
  int* expert_id = (int*)(ws + 67141632);                     // 32KB
  int* counts    = (int*)(ws + 67174400);
  int* offsets   = (int*)(ws + 67174528);
  int* cursor    = (int*)(ws + 67174784);
  int* tile_e    = (int*)(ws + 67174912);
  int* tile_p    = (int*)(ws + 67175424);
  int* n_tiles   = (int*)(ws + 67175936);

  hipMemsetAsync(counts, 0, NE * sizeof(int), stream);
  router_kernel<<<TOK / 8, 256, 0, stream>>>(x, gate_w, xbf, xsbf, expert_id, counts);
  scan_kernel<<<1, 64, 0, stream>>>(counts, offsets, cursor, tile_e, tile_p, n_tiles);
  perm_kernel<<<TOK / 256, 256, 0, stream>>>(expert_id, cursor, perm);

  gateup_kernel<false><<<dim3(TOK / BM, IDIM / BN), 256, 0, stream>>>(
      xbf, sgw, suw, act, perm, tile_e, tile_p, offsets, n_tiles);
  down_kernel<false><<<dim3(TOK / BM, H / BN), 256, 0, stream>>>(
      act, sdw, out, perm, tile_e, tile_p, offsets, n_tiles);
  gateup_kernel<true><<<dim3(MAX_TILES, IDIM / BN), 256, 0, stream>>>(
      xsbf, rgw, ruw, act, perm, tile_e, tile_p, offsets, n_tiles);
  down_kernel<true><<<dim3(MAX_TILES, H / BN), 256, 0, stream>>>(
      act, rdw, out, perm, tile_e, tile_p, offsets, n_tiles);
}